// Round 1
// baseline (514.382 us; speedup 1.0000x reference)
//
#include <hip/hip_runtime.h>
#include <hip/hip_bf16.h>
#include <stdint.h>

#define B_ 8
#define N_ 256
#define M_ 128
#define D_ 128

typedef __attribute__((ext_vector_type(8))) short short8;
typedef __attribute__((ext_vector_type(4))) short short4v;
typedef __attribute__((ext_vector_type(4))) float f32x4;

static __device__ __forceinline__ unsigned short f2bf(float x) {
    union { float f; unsigned int u; } c; c.f = x;
    unsigned int r = (c.u + 0x7FFFu + ((c.u >> 16) & 1u)) >> 16;
    return (unsigned short)r;
}

// ---------------- K0a: weight transposes (fp32) + bf16 casts (scaled 1/3) ----
__global__ void k0a_prep(const float* __restrict__ lin2_w, const float* __restrict__ lin3_w,
                         const float* __restrict__ mlp_w1, const float* __restrict__ mlp_w2,
                         const float* __restrict__ linv1_w, const float* __restrict__ linv2_w,
                         const float* __restrict__ linv3_w,
                         float* __restrict__ wT2, float* __restrict__ wT3,
                         float* __restrict__ wTm1, float* __restrict__ wTm2,
                         unsigned short* __restrict__ w1b, unsigned short* __restrict__ w2b,
                         unsigned short* __restrict__ w3b) {
    int gid = blockIdx.x * 256 + threadIdx.x;
    int task = gid >> 14;
    int idx = gid & 16383;
    if (task < 4) {
        int e = idx & 127, dd = idx >> 7;
        const float* src = task == 0 ? lin2_w : task == 1 ? lin3_w : task == 2 ? mlp_w1 : mlp_w2;
        float* dst = task == 0 ? wT2 : task == 1 ? wT3 : task == 2 ? wTm1 : wTm2;
        dst[dd * 128 + e] = src[e * 128 + dd];
    } else {
        const float* src = task == 4 ? linv1_w : task == 5 ? linv2_w : linv3_w;
        unsigned short* dst = task == 4 ? w1b : task == 5 ? w2b : w3b;
        dst[idx] = f2bf(src[idx] * (1.0f / 3.0f));
    }
}

// ---------------- K0b: s_v2t[b,d] = sum_m gv2[b,m,m,d] ------------------------
__global__ void k0b_trace(const float* __restrict__ gv2, float* __restrict__ s_v2t) {
    int gid = blockIdx.x * 256 + threadIdx.x;   // 1024 total
    int b = gid >> 7, dd = gid & 127;
    const float* p = gv2 + (size_t)b * (M_ * M_ * D_) + dd;
    float acc = 0.f;
    #pragma unroll 4
    for (int m = 0; m < 128; ++m) acc += p[(size_t)m * 16512];   // (m*128+m)*128
    s_v2t[gid] = acc;
}

// ---------------- K0c: g1[b,e] = (lin1(s_v2t)+b1)*gs --------------------------
__global__ void k0c_g1(const float* __restrict__ s_v2t, const float* __restrict__ lin1_w,
                       const float* __restrict__ lin1_b, const float* __restrict__ gs,
                       float* __restrict__ g1) {
    __shared__ float sv[128];
    int b = blockIdx.x, e = threadIdx.x;
    sv[e] = s_v2t[b * 128 + e];
    __syncthreads();
    const float* w = lin1_w + e * 128;
    float acc = 0.f;
    #pragma unroll 4
    for (int dd = 0; dd < 128; ++dd) acc = fmaf(sv[dd], w[dd], acc);
    g1[b * 128 + e] = (acc + lin1_b[e]) * gs[b * 128 + e];
}

// ---------------- K1: T[b,n,c,d] = sum_m v[b,n,m,d]*gv2[b,m,c,d] --------------
// lane=d outer-product; block tile 16n x 8c x 128d; grid swizzled so each b
// stays on one XCD (lb%8==b under round-robin dispatch).
__global__ __launch_bounds__(256, 2) void k1_T(const float* __restrict__ v,
                                               const float* __restrict__ gv2,
                                               float* __restrict__ Tout) {
    int lb = blockIdx.x;
    int b = lb & 7;
    int inner = lb >> 3;
    int ct = inner & 15;
    int nt = inner >> 4;
    int t = threadIdx.x;
    int d = t & 127;
    int p = t >> 7;
    int n0 = nt * 16 + p * 8;
    int c0 = ct * 8;
    const float* vp = v + (size_t)(b * N_ + n0) * (M_ * D_) + d;
    const float* gp = gv2 + ((size_t)b * M_ * M_ + c0) * D_ + d;
    float acc[8][8];
    #pragma unroll
    for (int i = 0; i < 8; ++i)
        #pragma unroll
        for (int j = 0; j < 8; ++j) acc[i][j] = 0.f;
    for (int m = 0; m < 128; ++m) {
        float vr[8], gr[8];
        #pragma unroll
        for (int i = 0; i < 8; ++i) vr[i] = vp[(size_t)i * 16384 + m * 128];
        #pragma unroll
        for (int j = 0; j < 8; ++j) gr[j] = gp[(size_t)m * 16384 + j * 128];
        #pragma unroll
        for (int i = 0; i < 8; ++i)
            #pragma unroll
            for (int j = 0; j < 8; ++j) acc[i][j] = fmaf(vr[i], gr[j], acc[i][j]);
    }
    #pragma unroll
    for (int i = 0; i < 8; ++i)
        #pragma unroll
        for (int j = 0; j < 8; ++j)
            Tout[((size_t)(b * N_ + n0 + i) * M_ + c0 + j) * D_ + d] = acc[i][j];
}

// ---------------- K2: v_new = [T | s*gv | gs*v] @ [W1;W2;W3]^T (bf16 MFMA) ----
// In-place over T region of d_out. 64 rows x 128 e per block, K=384.
__global__ __launch_bounds__(256, 2) void k2_vnew(
        const float* __restrict__ s, const float* __restrict__ v,
        const float* __restrict__ gs, const float* __restrict__ gv,
        const unsigned short* __restrict__ w1b, const unsigned short* __restrict__ w2b,
        const unsigned short* __restrict__ w3b,
        float* __restrict__ vnew) {
    __shared__ short Asm[64][392];   // 384 + 8 bf16 pad -> conflict-free b128
    int t = threadIdx.x;
    int rowbase = blockIdx.x * 64;
    int b = rowbase >> 15;
    int n = (rowbase >> 7) & 255;
    int cbase = rowbase & 127;       // 0 or 64
    const float* Trow = vnew + (size_t)rowbase * 128;
    const float* srow = s + (size_t)(b * N_ + n) * D_;
    const float* gsrow = gs + b * D_;
    const float* gvb = gv + ((size_t)b * M_ + cbase) * D_;
    const float* vrow = v + ((size_t)(b * N_ + n) * M_ + cbase) * D_;
    #pragma unroll
    for (int i = 0; i < 8; ++i) {
        int vi = i * 256 + t;
        int r = vi >> 5;
        int d0 = (vi & 31) * 4;
        float4 t4 = *(const float4*)(Trow + r * 128 + d0);
        float4 s4 = *(const float4*)(srow + d0);
        float4 g4 = *(const float4*)(gvb + r * 128 + d0);
        float4 q4 = *(const float4*)(gsrow + d0);
        float4 v4 = *(const float4*)(vrow + r * 128 + d0);
        *(short4v*)&Asm[r][d0] = (short4v){(short)f2bf(t4.x), (short)f2bf(t4.y),
                                           (short)f2bf(t4.z), (short)f2bf(t4.w)};
        *(short4v*)&Asm[r][128 + d0] = (short4v){(short)f2bf(s4.x * g4.x), (short)f2bf(s4.y * g4.y),
                                                 (short)f2bf(s4.z * g4.z), (short)f2bf(s4.w * g4.w)};
        *(short4v*)&Asm[r][256 + d0] = (short4v){(short)f2bf(q4.x * v4.x), (short)f2bf(q4.y * v4.y),
                                                 (short)f2bf(q4.z * v4.z), (short)f2bf(q4.w * v4.w)};
    }
    __syncthreads();
    int w = t >> 6;
    int lane = t & 63;
    int ln15 = lane & 15;
    int kgrp = lane >> 4;
    int wr = w * 16;
    short8 a[12];
    #pragma unroll
    for (int kk = 0; kk < 12; ++kk)
        a[kk] = *(const short8*)&Asm[wr + ln15][kk * 32 + kgrp * 8];
    #pragma unroll
    for (int ctile = 0; ctile < 8; ++ctile) {
        f32x4 acc = {0.f, 0.f, 0.f, 0.f};
        #pragma unroll
        for (int kk = 0; kk < 12; ++kk) {
            const unsigned short* wp = (kk < 4) ? w1b : (kk < 8) ? w2b : w3b;
            int kd = (kk & 3) * 32 + kgrp * 8;
            short8 bv = *(const short8*)&wp[(ctile * 16 + ln15) * 128 + kd];
            acc = __builtin_amdgcn_mfma_f32_16x16x32_bf16(a[kk], bv, acc, 0, 0, 0);
        }
        #pragma unroll
        for (int q = 0; q < 4; ++q) {
            int rowl = wr + kgrp * 4 + q;
            vnew[(size_t)(rowbase + rowl) * 128 + ctile * 16 + ln15] = acc[q];
        }
    }
}

// ---------------- K3: s_vv[b,n,d] = sum_m gv[b,m,d]*v_new[b,n,m,d] ------------
__global__ void k3_svv(const float* __restrict__ gv, const float* __restrict__ vnew,
                       float* __restrict__ svv) {
    int gid = blockIdx.x * 256 + threadIdx.x;
    int bn = gid >> 7, d = gid & 127;
    int b = bn >> 8;
    const float* vp = vnew + (size_t)bn * 16384 + d;
    const float* gp = gv + (size_t)b * 16384 + d;
    float acc = 0.f;
    #pragma unroll 4
    for (int m = 0; m < 128; ++m) acc = fmaf(gp[m * 128], vp[m * 128], acc);
    svv[gid] = acc;
}

// ---------------- K4: s-path linears + products + MLP -------------------------
__global__ __launch_bounds__(256) void k4_spath(
        const float* __restrict__ s, const float* __restrict__ svv,
        const float* __restrict__ g1,
        const float* __restrict__ wT2, const float* __restrict__ lin2_b,
        const float* __restrict__ wT3, const float* __restrict__ lin3_b,
        const float* __restrict__ wTm1, const float* __restrict__ mlp_b1,
        const float* __restrict__ wTm2, const float* __restrict__ mlp_b2,
        float* __restrict__ sout) {
    __shared__ float xs[8][128], xv[8][128], pre[8][128], hbuf[8][128];
    int t = threadIdx.x;
    int rowb = blockIdx.x * 8;       // bn base, same b within block
    int b = rowb >> 8;
    #pragma unroll
    for (int i = 0; i < 4; ++i) {
        int vi = i * 256 + t;
        int r = vi >> 7, dd = vi & 127;
        xs[r][dd] = s[(size_t)(rowb + r) * 128 + dd];
        xv[r][dd] = svv[(size_t)(rowb + r) * 128 + dd];
    }
    __syncthreads();
    int e = t & 127, h2 = t >> 7;
    float b2 = lin2_b[e], b3 = lin3_b[e], g1v = g1[b * 128 + e];
    float a2[4] = {b2, b2, b2, b2}, a3[4] = {b3, b3, b3, b3};
    for (int dd = 0; dd < 128; ++dd) {
        float w2 = wT2[dd * 128 + e], w3 = wT3[dd * 128 + e];
        #pragma unroll
        for (int r = 0; r < 4; ++r) {
            a2[r] = fmaf(xs[h2 * 4 + r][dd], w2, a2[r]);
            a3[r] = fmaf(xv[h2 * 4 + r][dd], w3, a3[r]);
        }
    }
    #pragma unroll
    for (int r = 0; r < 4; ++r) pre[h2 * 4 + r][e] = g1v * a2[r] * a3[r];
    __syncthreads();
    float bm1 = mlp_b1[e];
    float ah[4] = {bm1, bm1, bm1, bm1};
    for (int dd = 0; dd < 128; ++dd) {
        float w = wTm1[dd * 128 + e];
        #pragma unroll
        for (int r = 0; r < 4; ++r) ah[r] = fmaf(pre[h2 * 4 + r][dd], w, ah[r]);
    }
    #pragma unroll
    for (int r = 0; r < 4; ++r) hbuf[h2 * 4 + r][e] = fmaxf(ah[r], 0.f);
    __syncthreads();
    float bm2 = mlp_b2[e];
    float ao[4] = {bm2, bm2, bm2, bm2};
    for (int dd = 0; dd < 128; ++dd) {
        float w = wTm2[dd * 128 + e];
        #pragma unroll
        for (int r = 0; r < 4; ++r) ao[r] = fmaf(hbuf[h2 * 4 + r][dd], w, ao[r]);
    }
    #pragma unroll
    for (int r = 0; r < 4; ++r) sout[(size_t)(rowb + h2 * 4 + r) * 128 + e] = ao[r];
}

extern "C" void kernel_launch(void* const* d_in, const int* in_sizes, int n_in,
                              void* d_out, int out_size, void* d_ws, size_t ws_size,
                              hipStream_t stream) {
    const float* s       = (const float*)d_in[0];
    const float* v       = (const float*)d_in[1];
    const float* gs      = (const float*)d_in[2];
    const float* gv      = (const float*)d_in[3];
    const float* gv2     = (const float*)d_in[4];
    const float* lin1_w  = (const float*)d_in[5];
    const float* lin1_b  = (const float*)d_in[6];
    const float* lin2_w  = (const float*)d_in[7];
    const float* lin2_b  = (const float*)d_in[8];
    const float* lin3_w  = (const float*)d_in[9];
    const float* lin3_b  = (const float*)d_in[10];
    const float* linv1_w = (const float*)d_in[11];
    const float* linv2_w = (const float*)d_in[12];
    const float* linv3_w = (const float*)d_in[13];
    const float* mlp_w1  = (const float*)d_in[14];
    const float* mlp_b1  = (const float*)d_in[15];
    const float* mlp_w2  = (const float*)d_in[16];
    const float* mlp_b2  = (const float*)d_in[17];

    float* sout = (float*)d_out;
    float* vnew = (float*)d_out + 262144;   // v_new region; also T scratch

    float* wsf   = (float*)d_ws;
    float* wT2   = wsf;
    float* wT3   = wsf + 16384;
    float* wTm1  = wsf + 32768;
    float* wTm2  = wsf + 49152;
    float* s_v2t = wsf + 65536;
    float* g1    = wsf + 66560;
    float* svv   = wsf + 67584;
    unsigned short* w1b = (unsigned short*)(wsf + 329728);
    unsigned short* w2b = w1b + 16384;
    unsigned short* w3b = w1b + 32768;

    k0a_prep<<<448, 256, 0, stream>>>(lin2_w, lin3_w, mlp_w1, mlp_w2,
                                      linv1_w, linv2_w, linv3_w,
                                      wT2, wT3, wTm1, wTm2, w1b, w2b, w3b);
    k0b_trace<<<4, 256, 0, stream>>>(gv2, s_v2t);
    k0c_g1<<<8, 128, 0, stream>>>(s_v2t, lin1_w, lin1_b, gs, g1);
    k1_T<<<2048, 256, 0, stream>>>(v, gv2, vnew);
    k2_vnew<<<4096, 256, 0, stream>>>(s, v, gs, gv, w1b, w2b, w3b, vnew);
    k3_svv<<<1024, 256, 0, stream>>>(gv, vnew, svv);
    k4_spath<<<256, 256, 0, stream>>>(s, svv, g1, wT2, lin2_b, wT3, lin3_b,
                                      wTm1, mlp_b1, wTm2, mlp_b2, sout);
}

// Round 2
// 387.441 us; speedup vs baseline: 1.3276x; 1.3276x over previous
//
#include <hip/hip_runtime.h>
#include <hip/hip_bf16.h>
#include <stdint.h>

#define B_ 8
#define N_ 256
#define M_ 128
#define D_ 128

typedef __attribute__((ext_vector_type(8))) short short8;
typedef __attribute__((ext_vector_type(4))) short short4v;
typedef __attribute__((ext_vector_type(4))) float f32x4;

static __device__ __forceinline__ unsigned short f2bf(float x) {
    union { float f; unsigned int u; } c; c.f = x;
    unsigned int r = (c.u + 0x7FFFu + ((c.u >> 16) & 1u)) >> 16;
    return (unsigned short)r;
}

// ---------------- K0a: weight transposes (fp32) + bf16 casts (scaled 1/3) ----
__global__ void k0a_prep(const float* __restrict__ lin2_w, const float* __restrict__ lin3_w,
                         const float* __restrict__ mlp_w1, const float* __restrict__ mlp_w2,
                         const float* __restrict__ linv1_w, const float* __restrict__ linv2_w,
                         const float* __restrict__ linv3_w,
                         float* __restrict__ wT2, float* __restrict__ wT3,
                         float* __restrict__ wTm1, float* __restrict__ wTm2,
                         unsigned short* __restrict__ w1b, unsigned short* __restrict__ w2b,
                         unsigned short* __restrict__ w3b) {
    int gid = blockIdx.x * 256 + threadIdx.x;
    int task = gid >> 14;
    int idx = gid & 16383;
    if (task < 4) {
        int e = idx & 127, dd = idx >> 7;
        const float* src = task == 0 ? lin2_w : task == 1 ? lin3_w : task == 2 ? mlp_w1 : mlp_w2;
        float* dst = task == 0 ? wT2 : task == 1 ? wT3 : task == 2 ? wTm1 : wTm2;
        dst[dd * 128 + e] = src[e * 128 + dd];
    } else {
        const float* src = task == 4 ? linv1_w : task == 5 ? linv2_w : linv3_w;
        unsigned short* dst = task == 4 ? w1b : task == 5 ? w2b : w3b;
        dst[idx] = f2bf(src[idx] * (1.0f / 3.0f));
    }
}

// ---------------- K0b: s_v2t[b,d] = sum_m gv2[b,m,m,d] ------------------------
// one wave per (b,d): 1024 blocks x 64 lanes, shuffle-reduce.
__global__ void k0b_trace(const float* __restrict__ gv2, float* __restrict__ s_v2t) {
    int b = blockIdx.x >> 7, d = blockIdx.x & 127;
    int lane = threadIdx.x;
    const float* p = gv2 + (size_t)b * (M_ * M_ * D_) + d;
    float acc = p[(size_t)lane * 16512] + p[(size_t)(lane + 64) * 16512];
    #pragma unroll
    for (int s = 32; s; s >>= 1) acc += __shfl_down(acc, s);
    if (lane == 0) s_v2t[b * 128 + d] = acc;
}

// ---------------- K0c: g1[b,e] = (lin1(s_v2t)+b1)*gs --------------------------
__global__ void k0c_g1(const float* __restrict__ s_v2t, const float* __restrict__ lin1_w,
                       const float* __restrict__ lin1_b, const float* __restrict__ gs,
                       float* __restrict__ g1) {
    __shared__ float sv[128];
    int b = blockIdx.x, e = threadIdx.x;
    sv[e] = s_v2t[b * 128 + e];
    __syncthreads();
    const float* w = lin1_w + e * 128;
    float acc = 0.f;
    #pragma unroll 4
    for (int dd = 0; dd < 128; ++dd) acc = fmaf(sv[dd], w[dd], acc);
    g1[b * 128 + e] = (acc + lin1_b[e]) * gs[b * 128 + e];
}

// ---------------- K1': T2 = batched per-d GEMM via bf16 MFMA ------------------
// T_d[n,c] = sum_m V_d[n,m] * G_d[m,c].  Block = (b, dc:8d, nt:64n, ch:64c),
// 8 waves, wave = one d plane, acc 64 f32 (4x4 tiles of 16x16).
// Output: bf16, blocked layout inside v_new region of d_out:
//   ushort addr = kb*16384 + d*64 + r, kb = (b*256+n)*2+ch, r = c - ch*64.
// (= first half of K2-block kb's own 8192-float output region -> no race.)
__global__ __launch_bounds__(512, 4) void k1_T2(const float* __restrict__ v,
                                                const float* __restrict__ gv2,
                                                unsigned short* __restrict__ t2base) {
    __shared__ unsigned short sm[40960];   // A:[8][64][40]@0  B:[8][64][40]@20480; Lout overlays
    int bid = blockIdx.x;
    int b = bid & 7;                       // XCD-pinned per b
    int r = bid >> 3;
    int nt = r & 3, ch = (r >> 2) & 1, dc = r >> 3;
    int n0 = nt * 64, c0 = ch * 64, d0 = dc * 8;
    int t = threadIdx.x;
    int w = t >> 6, lane = t & 63, ln15 = lane & 15, kg = lane >> 4;

    f32x4 acc[4][4];
    #pragma unroll
    for (int i = 0; i < 4; ++i)
        #pragma unroll
        for (int j = 0; j < 4; ++j) acc[i][j] = (f32x4){0.f, 0.f, 0.f, 0.f};

    int d0l = (t & 1) * 4;
    int am = (t >> 1) & 31, anb = t >> 6;       // A staging coords
    int bc = (t >> 1) & 63, bmb = t >> 7;       // B staging coords

    for (int mc = 0; mc < 4; ++mc) {
        int m0 = mc * 32;
        {   // stage A: v[b, n0:n0+64, m0:m0+32, d0:d0+8] -> sm[d][n][m]
            const float* src = v + (((size_t)(b * N_ + n0) * M_ + m0 + am) * D_ + d0 + d0l);
            #pragma unroll
            for (int p = 0; p < 8; ++p) {
                int n = p * 8 + anb;
                float4 x = *(const float4*)(src + (size_t)n * (M_ * D_));
                #pragma unroll
                for (int j = 0; j < 4; ++j)
                    sm[(d0l + j) * 2560 + n * 40 + am] = f2bf(((const float*)&x)[j]);
            }
        }
        {   // stage B: gv2[b, m0:m0+32, c0:c0+64, d0:d0+8] -> sm[20480 + d][c][m]
            const float* src = gv2 + (((size_t)(b * M_ + m0) * M_ + c0 + bc) * D_ + d0 + d0l);
            #pragma unroll
            for (int p = 0; p < 8; ++p) {
                int m = p * 4 + bmb;
                float4 x = *(const float4*)(src + (size_t)m * (M_ * D_));
                #pragma unroll
                for (int j = 0; j < 4; ++j)
                    sm[20480 + (d0l + j) * 2560 + bc * 40 + m] = f2bf(((const float*)&x)[j]);
            }
        }
        __syncthreads();
        short8 af[4], bf[4];
        #pragma unroll
        for (int i = 0; i < 4; ++i)
            af[i] = *(const short8*)&sm[w * 2560 + (i * 16 + ln15) * 40 + kg * 8];
        #pragma unroll
        for (int j = 0; j < 4; ++j)
            bf[j] = *(const short8*)&sm[20480 + w * 2560 + (j * 16 + ln15) * 40 + kg * 8];
        #pragma unroll
        for (int i = 0; i < 4; ++i)
            #pragma unroll
            for (int j = 0; j < 4; ++j)
                acc[i][j] = __builtin_amdgcn_mfma_f32_16x16x32_bf16(af[i], bf[j], acc[i][j], 0, 0, 0);
        __syncthreads();
    }
    // epilogue: acc -> Lout[n][dl][c] (overlays A/B region), then coalesced store
    #pragma unroll
    for (int i = 0; i < 4; ++i)
        #pragma unroll
        for (int j = 0; j < 4; ++j)
            #pragma unroll
            for (int q = 0; q < 4; ++q) {
                int n = i * 16 + kg * 4 + q;
                int c = j * 16 + ln15;
                sm[n * 512 + w * 64 + c] = f2bf(acc[i][j][q]);
            }
    __syncthreads();
    #pragma unroll
    for (int p = 0; p < 8; ++p) {
        int u = p * 512 + t;
        int n = u >> 6;
        int off = (u & 63) * 8;
        short8 x = *(const short8*)&sm[n * 512 + off];
        size_t kb = (size_t)(b * N_ + n0 + n) * 2 + ch;
        *(short8*)(t2base + kb * 16384 + dc * 512 + off) = x;
    }
}

// ---------------- K2': v_new = [T2 | s*gv | gs*v] @ [W1;W2;W3]^T (bf16 MFMA) --
// Reads its own block's T2 (bf16, d-major) then overwrites its region.
__global__ __launch_bounds__(256, 2) void k2_vnew(
        const float* __restrict__ s, const float* __restrict__ v,
        const float* __restrict__ gs, const float* __restrict__ gv,
        const unsigned short* __restrict__ w1b, const unsigned short* __restrict__ w2b,
        const unsigned short* __restrict__ w3b,
        float* __restrict__ vnew) {
    __shared__ short Asm[64][392];   // K = 384 + 8 pad
    int t = threadIdx.x;
    int rowbase = blockIdx.x * 64;   // kb = blockIdx.x
    int b = rowbase >> 15;
    int n = (rowbase >> 7) & 255;
    int cbase = rowbase & 127;       // 0 or 64
    // T-part: own T2 chunk, layout t2u[d*64 + r], 16KB contiguous
    const unsigned short* t2u = (const unsigned short*)vnew + (size_t)rowbase * 256;
    #pragma unroll
    for (int p = 0; p < 4; ++p) {
        int d = p * 32 + (t >> 3);
        int r0 = (t & 7) * 8;
        short8 x = *(const short8*)&t2u[d * 64 + r0];
        #pragma unroll
        for (int j = 0; j < 8; ++j) Asm[r0 + j][d] = x[j];
    }
    const float* srow = s + (size_t)(b * N_ + n) * D_;
    const float* gsrow = gs + b * D_;
    const float* gvb = gv + ((size_t)b * M_ + cbase) * D_;
    const float* vrow = v + ((size_t)(b * N_ + n) * M_ + cbase) * D_;
    #pragma unroll
    for (int i = 0; i < 8; ++i) {
        int vi = i * 256 + t;
        int r = vi >> 5;
        int d0 = (vi & 31) * 4;
        float4 s4 = *(const float4*)(srow + d0);
        float4 g4 = *(const float4*)(gvb + r * 128 + d0);
        float4 q4 = *(const float4*)(gsrow + d0);
        float4 v4 = *(const float4*)(vrow + r * 128 + d0);
        *(short4v*)&Asm[r][128 + d0] = (short4v){(short)f2bf(s4.x * g4.x), (short)f2bf(s4.y * g4.y),
                                                 (short)f2bf(s4.z * g4.z), (short)f2bf(s4.w * g4.w)};
        *(short4v*)&Asm[r][256 + d0] = (short4v){(short)f2bf(q4.x * v4.x), (short)f2bf(q4.y * v4.y),
                                                 (short)f2bf(q4.z * v4.z), (short)f2bf(q4.w * v4.w)};
    }
    __syncthreads();
    int w = t >> 6;
    int lane = t & 63;
    int ln15 = lane & 15;
    int kgrp = lane >> 4;
    int wr = w * 16;
    short8 a[12];
    #pragma unroll
    for (int kk = 0; kk < 12; ++kk)
        a[kk] = *(const short8*)&Asm[wr + ln15][kk * 32 + kgrp * 8];
    #pragma unroll
    for (int ctile = 0; ctile < 8; ++ctile) {
        f32x4 acc = {0.f, 0.f, 0.f, 0.f};
        #pragma unroll
        for (int kk = 0; kk < 12; ++kk) {
            const unsigned short* wp = (kk < 4) ? w1b : (kk < 8) ? w2b : w3b;
            int kd = (kk & 3) * 32 + kgrp * 8;
            short8 bv = *(const short8*)&wp[(ctile * 16 + ln15) * 128 + kd];
            acc = __builtin_amdgcn_mfma_f32_16x16x32_bf16(a[kk], bv, acc, 0, 0, 0);
        }
        #pragma unroll
        for (int q = 0; q < 4; ++q) {
            int rowl = wr + kgrp * 4 + q;
            vnew[(size_t)(rowbase + rowl) * 128 + ctile * 16 + ln15] = acc[q];
        }
    }
}

// ---------------- K3: s_vv[b,n,d] = sum_m gv[b,m,d]*v_new[b,n,m,d] ------------
__global__ void k3_svv(const float* __restrict__ gv, const float* __restrict__ vnew,
                       float* __restrict__ svv) {
    int gid = blockIdx.x * 256 + threadIdx.x;
    int bn = gid >> 7, d = gid & 127;
    int b = bn >> 8;
    const float* vp = vnew + (size_t)bn * 16384 + d;
    const float* gp = gv + (size_t)b * 16384 + d;
    float acc = 0.f;
    #pragma unroll 4
    for (int m = 0; m < 128; ++m) acc = fmaf(gp[m * 128], vp[m * 128], acc);
    svv[gid] = acc;
}

// ---------------- K4: s-path linears + products + MLP -------------------------
__global__ __launch_bounds__(256) void k4_spath(
        const float* __restrict__ s, const float* __restrict__ svv,
        const float* __restrict__ g1,
        const float* __restrict__ wT2, const float* __restrict__ lin2_b,
        const float* __restrict__ wT3, const float* __restrict__ lin3_b,
        const float* __restrict__ wTm1, const float* __restrict__ mlp_b1,
        const float* __restrict__ wTm2, const float* __restrict__ mlp_b2,
        float* __restrict__ sout) {
    __shared__ float xs[8][128], xv[8][128], pre[8][128], hbuf[8][128];
    int t = threadIdx.x;
    int rowb = blockIdx.x * 8;
    int b = rowb >> 8;
    #pragma unroll
    for (int i = 0; i < 4; ++i) {
        int vi = i * 256 + t;
        int r = vi >> 7, dd = vi & 127;
        xs[r][dd] = s[(size_t)(rowb + r) * 128 + dd];
        xv[r][dd] = svv[(size_t)(rowb + r) * 128 + dd];
    }
    __syncthreads();
    int e = t & 127, h2 = t >> 7;
    float b2 = lin2_b[e], b3 = lin3_b[e], g1v = g1[b * 128 + e];
    float a2[4] = {b2, b2, b2, b2}, a3[4] = {b3, b3, b3, b3};
    for (int dd = 0; dd < 128; ++dd) {
        float w2 = wT2[dd * 128 + e], w3 = wT3[dd * 128 + e];
        #pragma unroll
        for (int r = 0; r < 4; ++r) {
            a2[r] = fmaf(xs[h2 * 4 + r][dd], w2, a2[r]);
            a3[r] = fmaf(xv[h2 * 4 + r][dd], w3, a3[r]);
        }
    }
    #pragma unroll
    for (int r = 0; r < 4; ++r) pre[h2 * 4 + r][e] = g1v * a2[r] * a3[r];
    __syncthreads();
    float bm1 = mlp_b1[e];
    float ah[4] = {bm1, bm1, bm1, bm1};
    for (int dd = 0; dd < 128; ++dd) {
        float w = wTm1[dd * 128 + e];
        #pragma unroll
        for (int r = 0; r < 4; ++r) ah[r] = fmaf(pre[h2 * 4 + r][dd], w, ah[r]);
    }
    #pragma unroll
    for (int r = 0; r < 4; ++r) hbuf[h2 * 4 + r][e] = fmaxf(ah[r], 0.f);
    __syncthreads();
    float bm2 = mlp_b2[e];
    float ao[4] = {bm2, bm2, bm2, bm2};
    for (int dd = 0; dd < 128; ++dd) {
        float w = wTm2[dd * 128 + e];
        #pragma unroll
        for (int r = 0; r < 4; ++r) ao[r] = fmaf(hbuf[h2 * 4 + r][dd], w, ao[r]);
    }
    #pragma unroll
    for (int r = 0; r < 4; ++r) sout[(size_t)(rowb + h2 * 4 + r) * 128 + e] = ao[r];
}

extern "C" void kernel_launch(void* const* d_in, const int* in_sizes, int n_in,
                              void* d_out, int out_size, void* d_ws, size_t ws_size,
                              hipStream_t stream) {
    const float* s       = (const float*)d_in[0];
    const float* v       = (const float*)d_in[1];
    const float* gs      = (const float*)d_in[2];
    const float* gv      = (const float*)d_in[3];
    const float* gv2     = (const float*)d_in[4];
    const float* lin1_w  = (const float*)d_in[5];
    const float* lin1_b  = (const float*)d_in[6];
    const float* lin2_w  = (const float*)d_in[7];
    const float* lin2_b  = (const float*)d_in[8];
    const float* lin3_w  = (const float*)d_in[9];
    const float* lin3_b  = (const float*)d_in[10];
    const float* linv1_w = (const float*)d_in[11];
    const float* linv2_w = (const float*)d_in[12];
    const float* linv3_w = (const float*)d_in[13];
    const float* mlp_w1  = (const float*)d_in[14];
    const float* mlp_b1  = (const float*)d_in[15];
    const float* mlp_w2  = (const float*)d_in[16];
    const float* mlp_b2  = (const float*)d_in[17];

    float* sout = (float*)d_out;
    float* vnew = (float*)d_out + 262144;   // v_new region; first half of each
                                            // 64-row block doubles as T2 (bf16)

    float* wsf   = (float*)d_ws;
    float* wT2   = wsf;
    float* wT3   = wsf + 16384;
    float* wTm1  = wsf + 32768;
    float* wTm2  = wsf + 49152;
    float* s_v2t = wsf + 65536;
    float* g1    = wsf + 66560;
    float* svv   = wsf + 67584;
    unsigned short* w1b = (unsigned short*)(wsf + 329728);
    unsigned short* w2b = w1b + 16384;
    unsigned short* w3b = w1b + 32768;

    k0a_prep<<<448, 256, 0, stream>>>(lin2_w, lin3_w, mlp_w1, mlp_w2,
                                      linv1_w, linv2_w, linv3_w,
                                      wT2, wT3, wTm1, wTm2, w1b, w2b, w3b);
    k0b_trace<<<1024, 64, 0, stream>>>(gv2, s_v2t);
    k0c_g1<<<8, 128, 0, stream>>>(s_v2t, lin1_w, lin1_b, gs, g1);
    k1_T2<<<1024, 512, 0, stream>>>(v, gv2, (unsigned short*)vnew);
    k2_vnew<<<4096, 256, 0, stream>>>(s, v, gs, gv, w1b, w2b, w3b, vnew);
    k3_svv<<<1024, 256, 0, stream>>>(gv, vnew, svv);
    k4_spath<<<256, 256, 0, stream>>>(s, svv, g1, wT2, lin2_b, wT3, lin3_b,
                                      wTm1, mlp_b1, wTm2, mlp_b2, sout);
}